// Round 8
// baseline (422.658 us; speedup 1.0000x reference)
//
#include <hip/hip_runtime.h>
#include <math.h>

#define N_NODES 100000
#define N_EDGES 1600000
#define D_IN 256
#define D_OUT 128

// ---- workspace layout (bytes) ------------------------------------------
#define OFF_SUPPORT 0
#define OFF_COUNTS  51200000
#define OFF_CSREV   51600008
#define OFF_BSUMS   64400008
#define OFF_WTHI    64400416
#define OFF_WTLO    64465952

#define SCAN_CHUNK  1024
#define SCAN_BLOCKS ((N_NODES + SCAN_CHUNK - 1) / SCAN_CHUNK)  // 98

#define GB 128                                   // node rows per GEMM tile
#define GEMM_BLOCKS ((N_NODES + GB - 1) / GB)    // 782
#define EDGE_BLOCKS ((N_EDGES + 255) / 256)      // 6250
#define WCONV_BLOCKS ((D_IN * D_OUT) / 256)      // 128

typedef __attribute__((ext_vector_type(8))) short s8v;   // 8 bf16 = 4 VGPR
typedef __attribute__((ext_vector_type(4))) float f4v;   // mfma acc

__device__ __forceinline__ short f2bf(float x) {   // RNE fp32 -> bf16 bits
  unsigned u = __float_as_uint(x);
  unsigned r = u + 0x7FFF + ((u >> 16) & 1);
  return (short)(r >> 16);
}
__device__ __forceinline__ float bf2f(short h) {
  return __uint_as_float(((unsigned)(unsigned short)h) << 16);
}

// split 8 fp32 into bf16 hi/lo fragments (in-register)
__device__ __forceinline__ void cvt8(float4 a, float4 b, s8v& h, s8v& l) {
  float f[8] = {a.x, a.y, a.z, a.w, b.x, b.y, b.z, b.w};
#pragma unroll
  for (int i = 0; i < 8; i++) {
    short hh = f2bf(f[i]);
    h[i] = hh;
    l[i] = f2bf(f[i] - bf2f(hh));
  }
}

__device__ __forceinline__ void gload_lds16(const void* g, void* l) {
  __builtin_amdgcn_global_load_lds(
      (const __attribute__((address_space(1))) void*)g,
      (__attribute__((address_space(3))) void*)l, 16, 0, 0);
}

#define VMW(N)                                             \
  asm volatile("s_waitcnt vmcnt(" #N ")" ::: "memory");    \
  __builtin_amdgcn_sched_barrier(0)
#define SBAR()                    \
  __builtin_amdgcn_s_barrier();   \
  __builtin_amdgcn_sched_barrier(0)

// ---------------------------------------------------------------------------
// K_prep: wconv (128 blocks) || edge histogram + rank capture (6250 blocks).
// counts[] zeroed by hipMemsetAsync before this dispatch.
// ---------------------------------------------------------------------------
__global__ __launch_bounds__(256) void prep_kernel(
    const float* __restrict__ W, short* __restrict__ wt_hi,
    short* __restrict__ wt_lo, const int* __restrict__ erow,
    int* __restrict__ counts, int* __restrict__ pos_e) {
  if (blockIdx.x < WCONV_BLOCKS) {
    int idx = blockIdx.x * 256 + threadIdx.x;   // 0..32767
    int k = idx >> 7;
    int n = idx & 127;
    float v = W[idx];
    short h = f2bf(v);
    wt_hi[n * 256 + k] = h;
    wt_lo[n * 256 + k] = f2bf(v - bf2f(h));
  } else {
    int e = (blockIdx.x - WCONV_BLOCKS) * 256 + threadIdx.x;
    if (e < N_EDGES) pos_e[e] = atomicAdd(&counts[erow[e]], 1);
  }
}

// ---------------------------------------------------------------------------
// GEMM v6 body (verified round 6/7, ~70 us): B in LDS (ds_read = lgkm
// domain, does NOT drain vmcnt); A = direct float4 loads in a 3-deep
// register pipeline; fully unrolled with exact counted vmcnt gates
// 8,16,8,16,8,16,4,0; raw s_barrier only; B swizzled via DMA source addr.
// ---------------------------------------------------------------------------
__device__ __forceinline__ void gemm_body(
    int gb, const float* __restrict__ input, const short* __restrict__ wt_hi,
    const short* __restrict__ wt_lo, const float* __restrict__ b,
    float* __restrict__ support) {
  __shared__ short Bh[2][128][64];   // 32 KB: parity x col x k-quarter
  __shared__ short Bl[2][128][64];   // 32 KB
  const int t = threadIdx.x;
  const int lane = t & 63;
  const int wv = t >> 6;
  const int qm = lane & 15;
  const int quad = lane >> 4;
  const int node0 = gb * GB;

  int r0 = node0 + wv * 32 + qm;
  int r1 = r0 + 16;
  if (r0 > N_NODES - 1) r0 = N_NODES - 1;   // clamp; garbage never stored
  if (r1 > N_NODES - 1) r1 = N_NODES - 1;
  const float* a0p = input + (size_t)r0 * D_IN + quad * 8;
  const float* a1p = input + (size_t)r1 * D_IN + quad * 8;

  const int lrow = lane >> 3;
  const int lpc = lane & 7;
  auto stageB = [&](int q, int p) {
    const int rb = wv * 32;
#pragma unroll
    for (int j = 0; j < 4; ++j) {
      int n = rb + j * 8 + lrow;
      int sc = lpc ^ (n & 7);
      const short* sh = wt_hi + (size_t)n * 256 + q * 64 + sc * 8;
      const short* sl = wt_lo + (size_t)n * 256 + q * 64 + sc * 8;
      gload_lds16(sh, &Bh[p][rb + j * 8][0]);
      gload_lds16(sl, &Bl[p][rb + j * 8][0]);
    }
  };

  float4 A0[4], A1[4], A2[4];
  auto loadA = [&](float4* d, int s) {
    d[0] = *(const float4*)(a0p + s * 32);
    d[1] = *(const float4*)(a0p + s * 32 + 4);
    d[2] = *(const float4*)(a1p + s * 32);
    d[3] = *(const float4*)(a1p + s * 32 + 4);
  };

  f4v acc[2][8];
#pragma unroll
  for (int mt = 0; mt < 2; mt++)
#pragma unroll
    for (int nt = 0; nt < 8; nt++) acc[mt][nt] = (f4v){0.f, 0.f, 0.f, 0.f};

  s8v ah0, al0, ah1, al1;
  auto cvtA = [&](const float4* X) {
    cvt8(X[0], X[1], ah0, al0);
    cvt8(X[2], X[3], ah1, al1);
  };
  auto mfma8 = [&](int p, int si) {
#pragma unroll
    for (int nt = 0; nt < 8; ++nt) {
      int n = nt * 16 + qm;
      int pc = (si * 4 + quad) ^ (n & 7);
      s8v bh = *(const s8v*)&Bh[p][n][pc * 8];
      s8v bl = *(const s8v*)&Bl[p][n][pc * 8];
      acc[0][nt] = __builtin_amdgcn_mfma_f32_16x16x32_bf16(ah0, bh, acc[0][nt], 0, 0, 0);
      acc[0][nt] = __builtin_amdgcn_mfma_f32_16x16x32_bf16(ah0, bl, acc[0][nt], 0, 0, 0);
      acc[0][nt] = __builtin_amdgcn_mfma_f32_16x16x32_bf16(al0, bh, acc[0][nt], 0, 0, 0);
      acc[1][nt] = __builtin_amdgcn_mfma_f32_16x16x32_bf16(ah1, bh, acc[1][nt], 0, 0, 0);
      acc[1][nt] = __builtin_amdgcn_mfma_f32_16x16x32_bf16(ah1, bl, acc[1][nt], 0, 0, 0);
      acc[1][nt] = __builtin_amdgcn_mfma_f32_16x16x32_bf16(al1, bh, acc[1][nt], 0, 0, 0);
    }
  };

  // ---- prologue: queue = [B0:8, A0:4, A1:4, A2:4] ----
  stageB(0, 0);
  loadA(A0, 0);
  loadA(A1, 1);
  loadA(A2, 2);
  VMW(8);   // gate B0+A0
  SBAR();
  cvtA(A0);
  stageB(1, 1);
  loadA(A0, 3);
  mfma8(0, 0);
  VMW(16);  // gate A1
  cvtA(A1);
  loadA(A1, 4);
  mfma8(0, 1);
  VMW(8);   // gate A2+B1
  SBAR();
  cvtA(A2);
  stageB(2, 0);
  loadA(A2, 5);
  mfma8(1, 0);
  VMW(16);  // gate A3
  cvtA(A0);
  loadA(A0, 6);
  mfma8(1, 1);
  VMW(8);   // gate A4+B2
  SBAR();
  cvtA(A1);
  stageB(3, 1);
  loadA(A1, 7);
  mfma8(0, 0);
  VMW(16);  // gate A5
  cvtA(A2);
  mfma8(0, 1);
  VMW(4);   // gate A6+B3
  SBAR();
  cvtA(A0);
  mfma8(1, 0);
  VMW(0);   // gate A7
  cvtA(A1);
  mfma8(1, 1);

  // ---- epilogue ----
  float bias[8];
#pragma unroll
  for (int nt = 0; nt < 8; nt++) bias[nt] = b[nt * 16 + qm];
#pragma unroll
  for (int mt = 0; mt < 2; mt++) {
#pragma unroll
    for (int nt = 0; nt < 8; nt++) {
      int col = nt * 16 + qm;
#pragma unroll
      for (int r = 0; r < 4; r++) {
        int node = node0 + wv * 32 + mt * 16 + quad * 4 + r;
        if (node < N_NODES)
          support[(size_t)node * D_OUT + col] = acc[mt][nt][r] + bias[nt];
      }
    }
  }
}

// ---------------------------------------------------------------------------
// K_gemm_build: GEMM (782 blocks) || atomic-free CSR scatter (6250 blocks).
// The two are data-independent (build needs offsets+edges, gemm needs W+X);
// co-scheduling saves their serial sum.  Edge streams use NT loads; csr_ev
// store is PLAIN (agg rereads it soon -> keep in L2).
// ---------------------------------------------------------------------------
__global__ __launch_bounds__(256, 2) void gemm_build_kernel(
    const float* __restrict__ input, const short* __restrict__ wt_hi,
    const short* __restrict__ wt_lo, const float* __restrict__ b,
    float* __restrict__ support, const int* __restrict__ erow,
    const int* __restrict__ ecol, const float* __restrict__ eval,
    const int* __restrict__ offsets, const int* __restrict__ pos_e,
    long long* __restrict__ csr_ev) {
  if (blockIdx.x < GEMM_BLOCKS) {
    gemm_body(blockIdx.x, input, wt_hi, wt_lo, b, support);
  } else {
    int e = (blockIdx.x - GEMM_BLOCKS) * 256 + threadIdx.x;
    if (e < N_EDGES) {
      int r = __builtin_nontemporal_load(erow + e);
      int c = __builtin_nontemporal_load(ecol + e);
      int vb = __builtin_nontemporal_load((const int*)eval + e);
      int p = __builtin_nontemporal_load(pos_e + e);
      int idx = offsets[r] + p;
      long long packed = (unsigned int)c | ((long long)(unsigned int)vb << 32);
      csr_ev[idx] = packed;
    }
  }
}

// ---------------------------------------------------------------------------
// 3-phase exclusive scan over counts (verified)
// ---------------------------------------------------------------------------
__global__ __launch_bounds__(256) void scan_phase1(const int* __restrict__ counts,
                                                   int* __restrict__ bsums) {
  __shared__ int ts[256];
  int t = threadIdx.x;
  int idx0 = blockIdx.x * SCAN_CHUNK + t * 4;
  int s = 0;
#pragma unroll
  for (int i = 0; i < 4; i++)
    if (idx0 + i < N_NODES) s += counts[idx0 + i];
  ts[t] = s;
  __syncthreads();
#pragma unroll
  for (int off = 128; off > 0; off >>= 1) {
    if (t < off) ts[t] += ts[t + off];
    __syncthreads();
  }
  if (t == 0) bsums[blockIdx.x] = ts[0];
}

__global__ __launch_bounds__(128) void scan_phase2(int* __restrict__ bsums) {
  __shared__ int s[128];
  int t = threadIdx.x;
  int v = (t < SCAN_BLOCKS) ? bsums[t] : 0;
  s[t] = v;
  __syncthreads();
#pragma unroll
  for (int off = 1; off < 128; off <<= 1) {
    int x = (t >= off) ? s[t - off] : 0;
    __syncthreads();
    s[t] += x;
    __syncthreads();
  }
  if (t < SCAN_BLOCKS) bsums[t] = s[t] - v;  // exclusive
}

__global__ __launch_bounds__(256) void scan_phase3(int* __restrict__ counts,
                                                   const int* __restrict__ bsums) {
  __shared__ int ts[256];
  int t = threadIdx.x;
  int b = blockIdx.x;
  int idx0 = b * SCAN_CHUNK + t * 4;
  int v[4];
  int s = 0;
#pragma unroll
  for (int i = 0; i < 4; i++) {
    v[i] = (idx0 + i < N_NODES) ? counts[idx0 + i] : 0;
    s += v[i];
  }
  ts[t] = s;
  __syncthreads();
#pragma unroll
  for (int off = 1; off < 256; off <<= 1) {
    int x = (t >= off) ? ts[t - off] : 0;
    __syncthreads();
    ts[t] += x;
    __syncthreads();
  }
  int run = bsums[b] + ts[t] - s;
#pragma unroll
  for (int i = 0; i < 4; i++) {
    int idx = idx0 + i;
    if (idx < N_NODES) counts[idx] = run;
    run += v[i];
  }
  if (b == 0 && t == 0) counts[N_NODES] = N_EDGES;
}

// ---------------------------------------------------------------------------
// Gather-aggregate + fused tanh (verified round 6 form: plain loads).
// 32 lanes x float4 per row; always-8-wide predicated batches + pipelined
// edge prefetch.
// ---------------------------------------------------------------------------
__global__ __launch_bounds__(256) void agg_kernel(
    const int* __restrict__ offsets, const long long* __restrict__ csr_ev,
    const float* __restrict__ support, float* __restrict__ out) {
  int r = blockIdx.x * 8 + (threadIdx.x >> 5);
  int l4 = (threadIdx.x & 31) * 4;          // feature quad
  int beg = offsets[r];
  int end = offsets[r + 1];
  float4 acc = make_float4(0.f, 0.f, 0.f, 0.f);

  if (end > beg) {
    int ec[8], encol[8];
    float ev[8], env[8];
#pragma unroll
    for (int u = 0; u < 8; u++) {           // prologue batch (predicated)
      int idx = beg + u;
      int c = idx < end ? idx : end - 1;
      long long p = csr_ev[c];
      ec[u] = (int)(unsigned int)p;
      ev[u] = (idx < end) ? __uint_as_float((unsigned int)(p >> 32)) : 0.f;
    }
    for (int j = beg; j < end; j += 8) {
      int jn = j + 8;
      if (jn < end) {                       // prefetch next batch
#pragma unroll
        for (int u = 0; u < 8; u++) {
          int idx = jn + u;
          int c = idx < end ? idx : end - 1;
          long long p = csr_ev[c];
          encol[u] = (int)(unsigned int)p;
          env[u] = (idx < end) ? __uint_as_float((unsigned int)(p >> 32)) : 0.f;
        }
      }
      float4 s[8];
#pragma unroll
      for (int u = 0; u < 8; u++)
        s[u] = *(const float4*)(support + (size_t)ec[u] * D_OUT + l4);
#pragma unroll
      for (int u = 0; u < 8; u++) {
        acc.x = fmaf(ev[u], s[u].x, acc.x);
        acc.y = fmaf(ev[u], s[u].y, acc.y);
        acc.z = fmaf(ev[u], s[u].z, acc.z);
        acc.w = fmaf(ev[u], s[u].w, acc.w);
      }
#pragma unroll
      for (int u = 0; u < 8; u++) { ec[u] = encol[u]; ev[u] = env[u]; }
    }
  }
  *(float4*)(out + (size_t)r * D_OUT + l4) =
      make_float4(tanhf(acc.x), tanhf(acc.y), tanhf(acc.z), tanhf(acc.w));
}

extern "C" void kernel_launch(void* const* d_in, const int* in_sizes, int n_in,
                              void* d_out, int out_size, void* d_ws, size_t ws_size,
                              hipStream_t stream) {
  const float* input = (const float*)d_in[0];
  const int* erow = (const int*)d_in[1];
  const int* ecol = (const int*)d_in[2];
  const float* eval = (const float*)d_in[3];
  const float* W = (const float*)d_in[4];
  const float* b = (const float*)d_in[5];
  float* out = (float*)d_out;

  char* ws = (char*)d_ws;
  float* support = (float*)(ws + OFF_SUPPORT);
  int* counts = (int*)(ws + OFF_COUNTS);  // becomes offsets after scan
  long long* csr_ev = (long long*)(ws + OFF_CSREV);
  int* bsums = (int*)(ws + OFF_BSUMS);
  short* wt_hi = (short*)(ws + OFF_WTHI);
  short* wt_lo = (short*)(ws + OFF_WTLO);
  int* pos_e = (int*)d_out;  // d_out as scratch; agg overwrites it last

  hipMemsetAsync(ws + OFF_COUNTS, 0, (size_t)(N_NODES + 1) * 4, stream);

  // K_prep: wconv || histogram+rank (one atomic round)
  hipLaunchKernelGGL(prep_kernel, dim3(WCONV_BLOCKS + EDGE_BLOCKS), dim3(256),
                     0, stream, W, wt_hi, wt_lo, erow, counts, pos_e);
  // exclusive scan: counts -> offsets
  hipLaunchKernelGGL(scan_phase1, dim3(SCAN_BLOCKS), dim3(256), 0, stream,
                     counts, bsums);
  hipLaunchKernelGGL(scan_phase2, dim3(1), dim3(128), 0, stream, bsums);
  hipLaunchKernelGGL(scan_phase3, dim3(SCAN_BLOCKS), dim3(256), 0, stream,
                     counts, bsums);
  // K_gemm_build: MFMA GEMM || CSR scatter (independent; co-scheduled)
  hipLaunchKernelGGL(gemm_build_kernel, dim3(GEMM_BLOCKS + EDGE_BLOCKS),
                     dim3(256), 0, stream, input, wt_hi, wt_lo, b, support,
                     erow, ecol, eval, counts, pos_e, csr_ev);
  // out = tanh(A_csr * support)
  hipLaunchKernelGGL(agg_kernel, dim3(N_NODES / 8), dim3(256), 0, stream,
                     counts, csr_ev, support, out);
}

// Round 9
// 411.599 us; speedup vs baseline: 1.0269x; 1.0269x over previous
//
#include <hip/hip_runtime.h>
#include <math.h>

#define N_NODES 100000
#define N_EDGES 1600000
#define D_IN 256
#define D_OUT 128

// ---- workspace layout (bytes) ------------------------------------------
#define OFF_SUPPORT 0
#define OFF_COUNTS  51200000
#define OFF_CSREV   51600008
#define OFF_STATE   64400008   // unsigned[98] lookback states (old bsums slot)
#define OFF_WTHI    64400416
#define OFF_WTLO    64465952

#define SCAN_CHUNK  1024
#define SCAN_BLOCKS ((N_NODES + SCAN_CHUNK - 1) / SCAN_CHUNK)  // 98

#define GB 128                                   // node rows per GEMM tile
#define GEMM_BLOCKS ((N_NODES + GB - 1) / GB)    // 782
#define WCONV_BLOCKS ((D_IN * D_OUT) / 256)      // 128
#define HIST_BLOCKS ((N_EDGES + 2047) / 2048)    // 782 (8 edges/thread)
#define BUILD_BLOCKS ((N_EDGES + 2047) / 2048)   // 782

typedef __attribute__((ext_vector_type(8))) short s8v;   // 8 bf16 = 4 VGPR
typedef __attribute__((ext_vector_type(4))) float f4v;   // mfma acc

__device__ __forceinline__ short f2bf(float x) {   // RNE fp32 -> bf16 bits
  unsigned u = __float_as_uint(x);
  unsigned r = u + 0x7FFF + ((u >> 16) & 1);
  return (short)(r >> 16);
}
__device__ __forceinline__ float bf2f(short h) {
  return __uint_as_float(((unsigned)(unsigned short)h) << 16);
}

// split 8 fp32 into bf16 hi/lo fragments (in-register)
__device__ __forceinline__ void cvt8(float4 a, float4 b, s8v& h, s8v& l) {
  float f[8] = {a.x, a.y, a.z, a.w, b.x, b.y, b.z, b.w};
#pragma unroll
  for (int i = 0; i < 8; i++) {
    short hh = f2bf(f[i]);
    h[i] = hh;
    l[i] = f2bf(f[i] - bf2f(hh));
  }
}

__device__ __forceinline__ void gload_lds16(const void* g, void* l) {
  __builtin_amdgcn_global_load_lds(
      (const __attribute__((address_space(1))) void*)g,
      (__attribute__((address_space(3))) void*)l, 16, 0, 0);
}

#define VMW(N)                                             \
  asm volatile("s_waitcnt vmcnt(" #N ")" ::: "memory");    \
  __builtin_amdgcn_sched_barrier(0)
#define SBAR()                    \
  __builtin_amdgcn_s_barrier();   \
  __builtin_amdgcn_sched_barrier(0)

// ---------------------------------------------------------------------------
// K_prep: wconv (128 blocks) || batched histogram+rank (782 blocks, 8
// edges/thread, loads batched for MLP).  Block 0 also zeroes the lookback
// states (consumed by scan_kernel, which launches after this dispatch).
// counts[] zeroed by hipMemsetAsync before this dispatch.
// ---------------------------------------------------------------------------
__global__ __launch_bounds__(256) void prep_kernel(
    const float* __restrict__ W, short* __restrict__ wt_hi,
    short* __restrict__ wt_lo, const int* __restrict__ erow,
    int* __restrict__ counts, int* __restrict__ pos_e,
    unsigned* __restrict__ state) {
  const int t = threadIdx.x;
  if (blockIdx.x < WCONV_BLOCKS) {
    int idx = blockIdx.x * 256 + t;   // 0..32767
    int k = idx >> 7;
    int n = idx & 127;
    float v = W[idx];
    short h = f2bf(v);
    wt_hi[n * 256 + k] = h;
    wt_lo[n * 256 + k] = f2bf(v - bf2f(h));
    if (blockIdx.x == 0 && t < SCAN_BLOCKS) state[t] = 0;
  } else {
    int base = (blockIdx.x - WCONV_BLOCKS) * 2048 + t;
    int r[8];
#pragma unroll
    for (int u = 0; u < 8; u++) {
      int e = base + u * 256;
      r[u] = (e < N_EDGES) ? erow[e] : -1;
    }
#pragma unroll
    for (int u = 0; u < 8; u++) {
      int e = base + u * 256;
      if (r[u] >= 0) pos_e[e] = atomicAdd(&counts[r[u]], 1);
    }
  }
}

// ---------------------------------------------------------------------------
// Single-dispatch decoupled-lookback exclusive scan (98 blocks, all
// co-resident; AGG published before lookback -> progress guaranteed under
// any scheduling order).  state[b] = (sum<<2) | {0 invalid,1 agg,2 inc}.
// ---------------------------------------------------------------------------
__global__ __launch_bounds__(256) void scan_kernel(
    int* __restrict__ counts, unsigned* __restrict__ state) {
  __shared__ int ts[256];
  __shared__ int sprev;
  const int t = threadIdx.x;
  const int b = blockIdx.x;
  int idx0 = b * SCAN_CHUNK + t * 4;
  int v[4];
  int s = 0;
#pragma unroll
  for (int i = 0; i < 4; i++) {
    v[i] = (idx0 + i < N_NODES) ? counts[idx0 + i] : 0;
    s += v[i];
  }
  ts[t] = s;
  __syncthreads();
#pragma unroll
  for (int off = 1; off < 256; off <<= 1) {
    int x = (t >= off) ? ts[t - off] : 0;
    __syncthreads();
    ts[t] += x;
    __syncthreads();
  }
  int total = ts[255];
  if (t == 0)
    atomicExch(&state[b], ((unsigned)total << 2) | (b == 0 ? 2u : 1u));
  if (b == 0) {
    if (t == 0) sprev = 0;
  } else if (t < 64) {            // wave 0 does the lookback
    unsigned run = 0;
    int look = b - 1;
    for (;;) {
      int p = look - t;
      unsigned sv = 2u;           // virtual INC(0) for p < 0
      if (p >= 0) {
        do { sv = atomicAdd(&state[p], 0u); } while ((sv & 3u) == 0u);
      }
      unsigned long long mask = __ballot((sv & 3u) == 2u);
      int fl = (mask != 0ULL) ? (__ffsll((long long)mask) - 1) : 64;
      unsigned c = (t <= fl) ? (sv >> 2) : 0u;
#pragma unroll
      for (int o = 32; o > 0; o >>= 1) c += __shfl_down(c, o);
      if (t == 0) run += c;
      if (mask != 0ULL) break;
      look -= 64;
    }
    if (t == 0) {
      sprev = (int)run;
      atomicExch(&state[b], ((run + (unsigned)total) << 2) | 2u);
    }
  }
  __syncthreads();
  int run0 = sprev + ts[t] - s;   // exclusive prefix for this thread's chunk
#pragma unroll
  for (int i = 0; i < 4; i++) {
    int idx = idx0 + i;
    if (idx < N_NODES) counts[idx] = run0;
    run0 += v[i];
  }
  if (b == 0 && t == 0) counts[N_NODES] = N_EDGES;
}

// ---------------------------------------------------------------------------
// GEMM v6 body (verified rounds 6-8, ~70 us): B in LDS (ds_read = lgkm
// domain, does NOT drain vmcnt); A = direct float4 loads in a 3-deep
// register pipeline; fully unrolled with exact counted vmcnt gates
// 8,16,8,16,8,16,4,0; raw s_barrier only; B swizzled via DMA source addr.
// ---------------------------------------------------------------------------
__device__ __forceinline__ void gemm_body(
    int gb, const float* __restrict__ input, const short* __restrict__ wt_hi,
    const short* __restrict__ wt_lo, const float* __restrict__ b,
    float* __restrict__ support) {
  __shared__ short Bh[2][128][64];   // 32 KB: parity x col x k-quarter
  __shared__ short Bl[2][128][64];   // 32 KB
  const int t = threadIdx.x;
  const int lane = t & 63;
  const int wv = t >> 6;
  const int qm = lane & 15;
  const int quad = lane >> 4;
  const int node0 = gb * GB;

  int r0 = node0 + wv * 32 + qm;
  int r1 = r0 + 16;
  if (r0 > N_NODES - 1) r0 = N_NODES - 1;   // clamp; garbage never stored
  if (r1 > N_NODES - 1) r1 = N_NODES - 1;
  const float* a0p = input + (size_t)r0 * D_IN + quad * 8;
  const float* a1p = input + (size_t)r1 * D_IN + quad * 8;

  const int lrow = lane >> 3;
  const int lpc = lane & 7;
  auto stageB = [&](int q, int p) {
    const int rb = wv * 32;
#pragma unroll
    for (int j = 0; j < 4; ++j) {
      int n = rb + j * 8 + lrow;
      int sc = lpc ^ (n & 7);
      const short* sh = wt_hi + (size_t)n * 256 + q * 64 + sc * 8;
      const short* sl = wt_lo + (size_t)n * 256 + q * 64 + sc * 8;
      gload_lds16(sh, &Bh[p][rb + j * 8][0]);
      gload_lds16(sl, &Bl[p][rb + j * 8][0]);
    }
  };

  float4 A0[4], A1[4], A2[4];
  auto loadA = [&](float4* d, int s) {
    d[0] = *(const float4*)(a0p + s * 32);
    d[1] = *(const float4*)(a0p + s * 32 + 4);
    d[2] = *(const float4*)(a1p + s * 32);
    d[3] = *(const float4*)(a1p + s * 32 + 4);
  };

  f4v acc[2][8];
#pragma unroll
  for (int mt = 0; mt < 2; mt++)
#pragma unroll
    for (int nt = 0; nt < 8; nt++) acc[mt][nt] = (f4v){0.f, 0.f, 0.f, 0.f};

  s8v ah0, al0, ah1, al1;
  auto cvtA = [&](const float4* X) {
    cvt8(X[0], X[1], ah0, al0);
    cvt8(X[2], X[3], ah1, al1);
  };
  auto mfma8 = [&](int p, int si) {
#pragma unroll
    for (int nt = 0; nt < 8; ++nt) {
      int n = nt * 16 + qm;
      int pc = (si * 4 + quad) ^ (n & 7);
      s8v bh = *(const s8v*)&Bh[p][n][pc * 8];
      s8v bl = *(const s8v*)&Bl[p][n][pc * 8];
      acc[0][nt] = __builtin_amdgcn_mfma_f32_16x16x32_bf16(ah0, bh, acc[0][nt], 0, 0, 0);
      acc[0][nt] = __builtin_amdgcn_mfma_f32_16x16x32_bf16(ah0, bl, acc[0][nt], 0, 0, 0);
      acc[0][nt] = __builtin_amdgcn_mfma_f32_16x16x32_bf16(al0, bh, acc[0][nt], 0, 0, 0);
      acc[1][nt] = __builtin_amdgcn_mfma_f32_16x16x32_bf16(ah1, bh, acc[1][nt], 0, 0, 0);
      acc[1][nt] = __builtin_amdgcn_mfma_f32_16x16x32_bf16(ah1, bl, acc[1][nt], 0, 0, 0);
      acc[1][nt] = __builtin_amdgcn_mfma_f32_16x16x32_bf16(al1, bh, acc[1][nt], 0, 0, 0);
    }
  };

  // ---- prologue: queue = [B0:8, A0:4, A1:4, A2:4] ----
  stageB(0, 0);
  loadA(A0, 0);
  loadA(A1, 1);
  loadA(A2, 2);
  VMW(8);   // gate B0+A0
  SBAR();
  cvtA(A0);
  stageB(1, 1);
  loadA(A0, 3);
  mfma8(0, 0);
  VMW(16);  // gate A1
  cvtA(A1);
  loadA(A1, 4);
  mfma8(0, 1);
  VMW(8);   // gate A2+B1
  SBAR();
  cvtA(A2);
  stageB(2, 0);
  loadA(A2, 5);
  mfma8(1, 0);
  VMW(16);  // gate A3
  cvtA(A0);
  loadA(A0, 6);
  mfma8(1, 1);
  VMW(8);   // gate A4+B2
  SBAR();
  cvtA(A1);
  stageB(3, 1);
  loadA(A1, 7);
  mfma8(0, 0);
  VMW(16);  // gate A5
  cvtA(A2);
  mfma8(0, 1);
  VMW(4);   // gate A6+B3
  SBAR();
  cvtA(A0);
  mfma8(1, 0);
  VMW(0);   // gate A7
  cvtA(A1);
  mfma8(1, 1);

  // ---- epilogue ----
  float bias[8];
#pragma unroll
  for (int nt = 0; nt < 8; nt++) bias[nt] = b[nt * 16 + qm];
#pragma unroll
  for (int mt = 0; mt < 2; mt++) {
#pragma unroll
    for (int nt = 0; nt < 8; nt++) {
      int col = nt * 16 + qm;
#pragma unroll
      for (int r = 0; r < 4; r++) {
        int node = node0 + wv * 32 + mt * 16 + quad * 4 + r;
        if (node < N_NODES)
          support[(size_t)node * D_OUT + col] = acc[mt][nt][r] + bias[nt];
      }
    }
  }
}

// ---------------------------------------------------------------------------
// K_gemm_build: GEMM (782 blocks) || batched atomic-free CSR scatter
// (782 blocks, 8 edges/thread, all loads batched for MLP).  Independent
// work co-scheduled.  NT loads on stream-once edge data; PLAIN csr_ev
// store (agg rereads it -> keep in L2).
// ---------------------------------------------------------------------------
__global__ __launch_bounds__(256, 2) void gemm_build_kernel(
    const float* __restrict__ input, const short* __restrict__ wt_hi,
    const short* __restrict__ wt_lo, const float* __restrict__ b,
    float* __restrict__ support, const int* __restrict__ erow,
    const int* __restrict__ ecol, const float* __restrict__ eval,
    const int* __restrict__ offsets, const int* __restrict__ pos_e,
    long long* __restrict__ csr_ev) {
  if (blockIdx.x < GEMM_BLOCKS) {
    gemm_body(blockIdx.x, input, wt_hi, wt_lo, b, support);
  } else {
    int base = (blockIdx.x - GEMM_BLOCKS) * 2048 + threadIdx.x;
    int r[8], p[8];
#pragma unroll
    for (int u = 0; u < 8; u++) {
      int e = base + u * 256;
      bool ok = e < N_EDGES;
      r[u] = ok ? __builtin_nontemporal_load(erow + e) : -1;
      p[u] = ok ? __builtin_nontemporal_load(pos_e + e) : 0;
    }
    int off[8];
#pragma unroll
    for (int u = 0; u < 8; u++) off[u] = (r[u] >= 0) ? offsets[r[u]] : 0;
    long long pk[8];
#pragma unroll
    for (int u = 0; u < 8; u++) {
      int e = base + u * 256;
      if (r[u] >= 0) {
        int c = __builtin_nontemporal_load(ecol + e);
        int vb = __builtin_nontemporal_load((const int*)eval + e);
        pk[u] = (unsigned)c | ((long long)(unsigned)vb << 32);
      }
    }
#pragma unroll
    for (int u = 0; u < 8; u++)
      if (r[u] >= 0) csr_ev[off[u] + p[u]] = pk[u];
  }
}

// ---------------------------------------------------------------------------
// Gather-aggregate + fused tanh (verified form).  32 lanes x float4 per
// row; always-8-wide predicated batches + pipelined edge prefetch.
// ---------------------------------------------------------------------------
__global__ __launch_bounds__(256) void agg_kernel(
    const int* __restrict__ offsets, const long long* __restrict__ csr_ev,
    const float* __restrict__ support, float* __restrict__ out) {
  int r = blockIdx.x * 8 + (threadIdx.x >> 5);
  int l4 = (threadIdx.x & 31) * 4;          // feature quad
  int beg = offsets[r];
  int end = offsets[r + 1];
  float4 acc = make_float4(0.f, 0.f, 0.f, 0.f);

  if (end > beg) {
    int ec[8], encol[8];
    float ev[8], env[8];
#pragma unroll
    for (int u = 0; u < 8; u++) {           // prologue batch (predicated)
      int idx = beg + u;
      int c = idx < end ? idx : end - 1;
      long long p = csr_ev[c];
      ec[u] = (int)(unsigned int)p;
      ev[u] = (idx < end) ? __uint_as_float((unsigned int)(p >> 32)) : 0.f;
    }
    for (int j = beg; j < end; j += 8) {
      int jn = j + 8;
      if (jn < end) {                       // prefetch next batch
#pragma unroll
        for (int u = 0; u < 8; u++) {
          int idx = jn + u;
          int c = idx < end ? idx : end - 1;
          long long p = csr_ev[c];
          encol[u] = (int)(unsigned int)p;
          env[u] = (idx < end) ? __uint_as_float((unsigned int)(p >> 32)) : 0.f;
        }
      }
      float4 s[8];
#pragma unroll
      for (int u = 0; u < 8; u++)
        s[u] = *(const float4*)(support + (size_t)ec[u] * D_OUT + l4);
#pragma unroll
      for (int u = 0; u < 8; u++) {
        acc.x = fmaf(ev[u], s[u].x, acc.x);
        acc.y = fmaf(ev[u], s[u].y, acc.y);
        acc.z = fmaf(ev[u], s[u].z, acc.z);
        acc.w = fmaf(ev[u], s[u].w, acc.w);
      }
#pragma unroll
      for (int u = 0; u < 8; u++) { ec[u] = encol[u]; ev[u] = env[u]; }
    }
  }
  *(float4*)(out + (size_t)r * D_OUT + l4) =
      make_float4(tanhf(acc.x), tanhf(acc.y), tanhf(acc.z), tanhf(acc.w));
}

extern "C" void kernel_launch(void* const* d_in, const int* in_sizes, int n_in,
                              void* d_out, int out_size, void* d_ws, size_t ws_size,
                              hipStream_t stream) {
  const float* input = (const float*)d_in[0];
  const int* erow = (const int*)d_in[1];
  const int* ecol = (const int*)d_in[2];
  const float* eval = (const float*)d_in[3];
  const float* W = (const float*)d_in[4];
  const float* b = (const float*)d_in[5];
  float* out = (float*)d_out;

  char* ws = (char*)d_ws;
  float* support = (float*)(ws + OFF_SUPPORT);
  int* counts = (int*)(ws + OFF_COUNTS);  // becomes offsets after scan
  long long* csr_ev = (long long*)(ws + OFF_CSREV);
  unsigned* state = (unsigned*)(ws + OFF_STATE);
  short* wt_hi = (short*)(ws + OFF_WTHI);
  short* wt_lo = (short*)(ws + OFF_WTLO);
  int* pos_e = (int*)d_out;  // d_out as scratch; agg overwrites it last

  hipMemsetAsync(ws + OFF_COUNTS, 0, (size_t)(N_NODES + 1) * 4, stream);

  // K_prep: wconv || batched histogram+rank (+ lookback-state zeroing)
  hipLaunchKernelGGL(prep_kernel, dim3(WCONV_BLOCKS + HIST_BLOCKS), dim3(256),
                     0, stream, W, wt_hi, wt_lo, erow, counts, pos_e, state);
  // single-dispatch decoupled-lookback exclusive scan: counts -> offsets
  hipLaunchKernelGGL(scan_kernel, dim3(SCAN_BLOCKS), dim3(256), 0, stream,
                     counts, state);
  // K_gemm_build: MFMA GEMM || batched CSR scatter
  hipLaunchKernelGGL(gemm_build_kernel, dim3(GEMM_BLOCKS + BUILD_BLOCKS),
                     dim3(256), 0, stream, input, wt_hi, wt_lo, b, support,
                     erow, ecol, eval, counts, pos_e, csr_ev);
  // out = tanh(A_csr * support)
  hipLaunchKernelGGL(agg_kernel, dim3(N_NODES / 8), dim3(256), 0, stream,
                     counts, csr_ev, support, out);
}